// Round 9
// baseline (169.947 us; speedup 1.0000x reference)
//
#include <hip/hip_runtime.h>
#include <math.h>

#define NSITES 100000
#define NYEARS 20
#define HDIM 64

typedef _Float16 f16x8 __attribute__((ext_vector_type(8)));
typedef _Float16 hx2   __attribute__((ext_vector_type(2)));
typedef float f32x4 __attribute__((ext_vector_type(4)));

__device__ __forceinline__ float sigmoidf_(float x) { return 1.0f / (1.0f + __expf(-x)); }
// fast elu: __expf(x)-1 (error ~1e-7, far below tolerance; result is f16-truncated anyway)
__device__ __forceinline__ float eluf_(float x) { return x > 0.0f ? x : __expf(x) - 1.0f; }

// load 8 consecutive f32 (32B-aligned) -> f16x8
__device__ __forceinline__ f16x8 cvt8h_(const float* p) {
    float4 a = ((const float4*)p)[0];
    float4 b = ((const float4*)p)[1];
    f16x8 r;
    r[0] = (_Float16)a.x; r[1] = (_Float16)a.y; r[2] = (_Float16)a.z; r[3] = (_Float16)a.w;
    r[4] = (_Float16)b.x; r[5] = (_Float16)b.y; r[6] = (_Float16)b.z; r[7] = (_Float16)b.w;
    return r;
}

union FragU { hx2 h2[4]; f16x8 v; };

// R21: 1-WAVE BLOCKS. 64 threads x 16 sites, 6250 blocks (100000/16 exact, no
// tail). R12-R20 post-mortem: dur pinned at 44-48us while VALUBusy fell
// 49->29%, LDS 33.8->18.4KB, ILP doubled -- compute was filling idle slots.
// Wave lifetime ~11.5us vs ~1-2us issue floor: stall-dominated, and the
// 4-wave barrier-coupled block phases (stage->loop->epilogue) kept stalls
// from interleaving across blocks. This round removes ALL coupling:
//  - no weight staging: each lane loads its MFMA fragments DIRECTLY from
//    global (per-lane addresses). Per wave = exactly one copy of W_hh/W_h1
//    (32KB, L1/L2-hot: all 6250 waves read the same 48KB).
//  - LDS = logit buffers only (2560B). No overlay, no hazard.
//  - no cross-wave barriers (1 wave; __syncthreads = fence only).
//  - blocks flow continuously through SIMDs (fine-grained residency).
// launch_bounds(64,4): VGPR cap 128, live ~110 -- no spill expected
// (validity check: FETCH ~12-15MB / WRITE ~23MB; a jump = spill).
// Loop body = R20 (f16 MFMA + packed-f16 relu update), validated R8/R10
// permuted-output-row recurrence (lane's D regs ARE its next-round B-frag),
// heads as 5th m-tile, x from global pipelined one round ahead.
// Slot semantics: pL[s*20+k] = p-logit(h_k) k=0..19;
//                 psiL[s*20+k] = psi-logit(h_k) k=1..19, slot0 = psi0-logit.
__global__ __launch_bounds__(64, 4)
void rnet_kernel(const float* __restrict__ sxy0,
                 const float* __restrict__ sxy,
                 const float* __restrict__ oxy,
                 const float* __restrict__ W_h0, const float* __restrict__ b_h0,
                 const float* __restrict__ W_h1, const float* __restrict__ b_h1,
                 const float* __restrict__ W_ih, const float* __restrict__ b_ih,
                 const float* __restrict__ W_hh, const float* __restrict__ b_hh,
                 const float* __restrict__ W_psi0, const float* __restrict__ b_psi0,
                 const float* __restrict__ W_psi, const float* __restrict__ b_psi,
                 const float* __restrict__ W_p, const float* __restrict__ b_p,
                 float* __restrict__ out)
{
    const int lane = threadIdx.x;       // 0..63 (one wave)
    const int s = lane & 15;            // site within wave / A-row within tile
    const int q = lane >> 4;            // quad
    const int sq = s >> 2, sr = s & 3;
    const int base = blockIdx.x * 16;   // 6250 blocks, exact
    const int site = base + s;

    __shared__ __align__(16) float pL[16 * 20];     // p-logits  [site][k]
    __shared__ __align__(16) float psiL[16 * 20];   // psi-logits; slot0 = psi0

    float* __restrict__ out_psi0 = out;                 // [N]
    float* __restrict__ out_psi  = out + NSITES;        // [N,19]
    float* __restrict__ out_p    = out + 20 * NSITES;   // [N,20,2]

    // ==== h0 stage: hs = elu(s0*W_h0+b_h0) in B layout; h0 via permuted W_h1 ====
    f16x8 bf[2];
    {
        const float s0v = sxy0[site];
        f16x8 bf0[2];
#pragma unroll
        for (int kt = 0; kt < 2; ++kt) {
            const float* wp = W_h0 + kt * 32 + q * 8;
            const float* bp = b_h0 + kt * 32 + q * 8;
            float4 w0 = ((const float4*)wp)[0], w1 = ((const float4*)wp)[1];
            float4 c0 = ((const float4*)bp)[0], c1 = ((const float4*)bp)[1];
            float v[8];
            v[0] = eluf_(fmaf(s0v, w0.x, c0.x)); v[1] = eluf_(fmaf(s0v, w0.y, c0.y));
            v[2] = eluf_(fmaf(s0v, w0.z, c0.z)); v[3] = eluf_(fmaf(s0v, w0.w, c0.w));
            v[4] = eluf_(fmaf(s0v, w1.x, c1.x)); v[5] = eluf_(fmaf(s0v, w1.y, c1.y));
            v[6] = eluf_(fmaf(s0v, w1.z, c1.z)); v[7] = eluf_(fmaf(s0v, w1.w, c1.w));
#pragma unroll
            for (int j = 0; j < 8; ++j) bf0[kt][j] = (_Float16)v[j];
        }

        f32x4 acc[4];
#pragma unroll
        for (int mt = 0; mt < 4; ++mt) {
            const int dr = 32 * (mt >> 1) + 8 * q + 4 * (mt & 1);
            float4 b1 = *(const float4*)(b_h1 + dr);
            acc[mt][0] = b1.x; acc[mt][1] = b1.y; acc[mt][2] = b1.z; acc[mt][3] = b1.w;
        }
#pragma unroll
        for (int kt = 0; kt < 2; ++kt)
#pragma unroll
            for (int mt = 0; mt < 4; ++mt) {
                const int ar = 32 * (mt >> 1) + 8 * sq + 4 * (mt & 1) + sr;
                f16x8 a = cvt8h_(W_h1 + ar * HDIM + kt * 32 + q * 8);   // direct global
                acc[mt] = __builtin_amdgcn_mfma_f32_16x16x32_f16(a, bf0[kt], acc[mt], 0, 0, 0);
            }
        FragU f0, f1;
#pragma unroll
        for (int mt = 0; mt < 4; ++mt) {
            hx2 plo; plo[0] = (_Float16)eluf_(acc[mt][0]); plo[1] = (_Float16)eluf_(acc[mt][1]);
            hx2 phi; phi[0] = (_Float16)eluf_(acc[mt][2]); phi[1] = (_Float16)eluf_(acc[mt][3]);
            if (mt < 2) { f0.h2[mt * 2] = plo; f0.h2[mt * 2 + 1] = phi; }
            else        { f1.h2[(mt - 2) * 2] = plo; f1.h2[(mt - 2) * 2 + 1] = phi; }
        }
        bf[0] = f0.v;
        bf[1] = f1.v;
    }

    // ==== persistent loop state: fragments DIRECT from global (L1/L2-hot) ====
    f16x8 a_hh[4][2];
#pragma unroll
    for (int mt = 0; mt < 4; ++mt) {
        const int ar = 32 * (mt >> 1) + 8 * sq + 4 * (mt & 1) + sr;
#pragma unroll
        for (int kt = 0; kt < 2; ++kt)
            a_hh[mt][kt] = cvt8h_(W_hh + ar * HDIM + kt * 32 + q * 8);
    }
    f16x8 a_head[2];
    {
        const float* hrow = (s == 1) ? W_p : ((s == 2) ? W_psi0 : W_psi);
#pragma unroll
        for (int kt = 0; kt < 2; ++kt) a_head[kt] = cvt8h_(hrow + kt * 32 + q * 8);
    }
    f32x4 biasD[4];
    hx2 wih2[4][2];
#pragma unroll
    for (int mt = 0; mt < 4; ++mt) {
        const int dr = 32 * (mt >> 1) + 8 * q + 4 * (mt & 1);
        float4 bi = *(const float4*)(b_ih + dr);
        float4 bh = *(const float4*)(b_hh + dr);
        float4 wi = *(const float4*)(W_ih + dr);
        biasD[mt][0] = bi.x + bh.x; biasD[mt][1] = bi.y + bh.y;
        biasD[mt][2] = bi.z + bh.z; biasD[mt][3] = bi.w + bh.w;
        wih2[mt][0][0] = (_Float16)wi.x; wih2[mt][0][1] = (_Float16)wi.y;
        wih2[mt][1][0] = (_Float16)wi.z; wih2[mt][1][1] = (_Float16)wi.w;
    }
    f32x4 headC;
    headC[0] = (q == 0) ? b_psi[0]  : 0.0f;
    headC[1] = (q == 0) ? b_p[0]    : 0.0f;
    headC[2] = (q == 0) ? b_psi0[0] : 0.0f;
    headC[3] = 0.0f;
    const hx2 z2 = (hx2)(_Float16)0.0f;
    const float* __restrict__ xs_g = sxy + (size_t)site * 19;

    // ==== recurrence: ROLLED, x from global pipelined one round ahead ====
    float x = xs_g[0];                 // x for round t=1
#pragma unroll 1
    for (int t = 1; t < NYEARS; ++t) {
        float x_next = (t < NYEARS - 1) ? xs_g[t] : 0.0f;

        f32x4 acc[4], accH;
#pragma unroll
        for (int mt = 0; mt < 4; ++mt)
            acc[mt] = __builtin_amdgcn_mfma_f32_16x16x32_f16(a_hh[mt][0], bf[0], biasD[mt], 0, 0, 0);
        accH = __builtin_amdgcn_mfma_f32_16x16x32_f16(a_head[0], bf[0], headC, 0, 0, 0);
#pragma unroll
        for (int mt = 0; mt < 4; ++mt)
            acc[mt] = __builtin_amdgcn_mfma_f32_16x16x32_f16(a_hh[mt][1], bf[1], acc[mt], 0, 0, 0);
        accH = __builtin_amdgcn_mfma_f32_16x16x32_f16(a_head[1], bf[1], accH, 0, 0, 0);

        // packed-f16 relu update: hn = max(acc + x*wih, 0); result IS B-frag
        _Float16 xh = (_Float16)x;
        hx2 x2; x2[0] = xh; x2[1] = xh;
        FragU f0, f1;
#pragma unroll
        for (int mt = 0; mt < 4; ++mt) {
            hx2 plo; plo[0] = (_Float16)acc[mt][0]; plo[1] = (_Float16)acc[mt][1];
            hx2 phi; phi[0] = (_Float16)acc[mt][2]; phi[1] = (_Float16)acc[mt][3];
            plo = __builtin_elementwise_max(plo + x2 * wih2[mt][0], z2);
            phi = __builtin_elementwise_max(phi + x2 * wih2[mt][1], z2);
            if (mt < 2) { f0.h2[mt * 2] = plo; f0.h2[mt * 2 + 1] = phi; }
            else        { f1.h2[(mt - 2) * 2] = plo; f1.h2[(mt - 2) * 2 + 1] = phi; }
        }
        bf[0] = f0.v;
        bf[1] = f1.v;

        if (q == 0) {
            // accH is from bf = h_{t-1}: slot (t-1) semantics (R12-validated).
            pL[s * 20 + (t - 1)]   = accH[1];   // p-logit(h_{t-1}), slots 0..18
            psiL[s * 20 + (t - 1)] = accH[0];   // psi-logit(h_{t-1}); slot 0 dead
            if (t == 1) psiL[s * 20] = accH[2]; // overwrite dead slot 0 w/ psi0
        }
        x = x_next;
    }

    // ==== final heads on h_19 ====
    {
        f32x4 accH = __builtin_amdgcn_mfma_f32_16x16x32_f16(a_head[0], bf[0], headC, 0, 0, 0);
        accH = __builtin_amdgcn_mfma_f32_16x16x32_f16(a_head[1], bf[1], accH, 0, 0, 0);
        if (q == 0) {
            pL[s * 20 + 19]   = accH[1];   // p-logit(h_19)
            psiL[s * 20 + 19] = accH[0];   // psi-logit(h_19)
        }
    }

    __syncthreads();   // 1-wave block: LDS fence only

    // ==== epilogue: sigmoid + oxy, 64 threads over 16 sites (exact, no guards) ====
    const float wpo = W_p[HDIM];
    if (lane < 16) out_psi0[base + lane] = sigmoidf_(psiL[lane * 20]);
    // psi: 16*19 = 304 floats; flat i = s2*19 + c <- psiL[s2*20 + c+1]
#pragma unroll
    for (int r = 0; r < 5; ++r) {
        int i = r * 64 + lane;
        if (i < 16 * 19) {
            int s2 = i / 19, c = i - s2 * 19;
            out_psi[(size_t)base * 19 + i] = sigmoidf_(psiL[s2 * 20 + c + 1]);
        }
    }
    // p: 16*40 = 640 floats = 160 float4; float4 i4 -> logits pL[i4*2], pL[i4*2+1]
    const float4* oxy_b = (const float4*)(oxy + (size_t)base * 40);
    float4* outp_b = (float4*)(out_p + (size_t)base * 40);
#pragma unroll
    for (int r = 0; r < 3; ++r) {
        int i4 = r * 64 + lane;
        if (i4 < 160) {
            float4 ox = oxy_b[i4];
            float lg0 = pL[i4 * 2];
            float lg1 = pL[i4 * 2 + 1];
            float4 pv;
            pv.x = sigmoidf_(fmaf(wpo, ox.x, lg0));
            pv.y = sigmoidf_(fmaf(wpo, ox.y, lg0));
            pv.z = sigmoidf_(fmaf(wpo, ox.z, lg1));
            pv.w = sigmoidf_(fmaf(wpo, ox.w, lg1));
            outp_b[i4] = pv;
        }
    }
}

extern "C" void kernel_launch(void* const* d_in, const int* in_sizes, int n_in,
                              void* d_out, int out_size, void* d_ws, size_t ws_size,
                              hipStream_t stream) {
    const float* sxy0   = (const float*)d_in[0];
    const float* sxy    = (const float*)d_in[1];
    const float* oxy    = (const float*)d_in[2];
    const float* W_h0   = (const float*)d_in[3];
    const float* b_h0   = (const float*)d_in[4];
    const float* W_h1   = (const float*)d_in[5];
    const float* b_h1   = (const float*)d_in[6];
    const float* W_ih   = (const float*)d_in[7];
    const float* b_ih   = (const float*)d_in[8];
    const float* W_hh   = (const float*)d_in[9];
    const float* b_hh   = (const float*)d_in[10];
    const float* W_psi0 = (const float*)d_in[11];
    const float* b_psi0 = (const float*)d_in[12];
    const float* W_psi  = (const float*)d_in[13];
    const float* b_psi  = (const float*)d_in[14];
    const float* W_p    = (const float*)d_in[15];
    const float* b_p    = (const float*)d_in[16];

    float* out = (float*)d_out;

    dim3 block(64);
    dim3 grid(NSITES / 16);   // 6250 one-wave blocks, 16 sites each (exact)
    rnet_kernel<<<grid, block, 0, stream>>>(
        sxy0, sxy, oxy, W_h0, b_h0, W_h1, b_h1, W_ih, b_ih, W_hh, b_hh,
        W_psi0, b_psi0, W_psi, b_psi, W_p, b_p, out);
}

// Round 10
// 143.028 us; speedup vs baseline: 1.1882x; 1.1882x over previous
//
#include <hip/hip_runtime.h>
#include <math.h>

#define NSITES 100000
#define NYEARS 20
#define HDIM 64

typedef _Float16 f16x8 __attribute__((ext_vector_type(8)));
typedef _Float16 hx2   __attribute__((ext_vector_type(2)));
typedef float f32x4 __attribute__((ext_vector_type(4)));

__device__ __forceinline__ float sigmoidf_(float x) { return 1.0f / (1.0f + __expf(-x)); }
// fast elu: __expf(x)-1 (error ~1e-7, far below tolerance; result is f16-truncated anyway)
__device__ __forceinline__ float eluf_(float x) { return x > 0.0f ? x : __expf(x) - 1.0f; }

// load 8 consecutive f32 (32B-aligned) -> f16x8
__device__ __forceinline__ f16x8 cvt8h_(const float* p) {
    float4 a = ((const float4*)p)[0];
    float4 b = ((const float4*)p)[1];
    f16x8 r;
    r[0] = (_Float16)a.x; r[1] = (_Float16)a.y; r[2] = (_Float16)a.z; r[3] = (_Float16)a.w;
    r[4] = (_Float16)b.x; r[5] = (_Float16)b.y; r[6] = (_Float16)b.z; r[7] = (_Float16)b.w;
    return r;
}

union FragU { hx2 h2[4]; f16x8 v; };

// R22 = R21 (1-wave blocks) with the two induced defects repaired:
//  1. launch_bounds(64,2) instead of (64,4): R21's (64,4) made hipcc target a
//     64-VGPR budget and spill the loop state (WRITE 23->67MB, dur 77us) --
//     third allocator-sabotage regression (R14, R17, R21). Cap 256 = spill
//     impossible; live ~110 VGPR -> HW 4-waves/SIMD bucket anyway (residency
//     is set by ACTUAL VGPR, not by the bound).
//  2. xs staged back into a tiny LDS buffer (16x19x4 = 1216B): R21 read x
//     from global per iteration with only one-iteration pipeline cover
//     (~150cyc) vs L2 latency (~200+cyc). Intra-wave __syncthreads only --
//     no cross-wave coupling is reintroduced.
// Structure under test (A/B vs R20's 44us 4-wave staged blocks):
//  - 64 threads x 16 sites, 6250 blocks (exact, no tail)
//  - weights DIRECT from global per-lane (one copy of W_hh/W_h1 per wave;
//    48KB working set shared by all waves -> L2-hot)
//  - LDS = logits (2560B) + xs (1216B); no overlay, no weight staging
//  - zero cross-wave barriers; blocks flow through SIMDs fine-grained
// Loop body = R20 (f16 MFMA + packed-f16 relu), validated R8/R10 permuted
// output-row recurrence (lane's D regs ARE its next-round B-frag), heads as
// 5th m-tile. Slot semantics: pL[s*20+k]=p-logit(h_k) k=0..19;
// psiL[s*20+k]=psi-logit(h_k) k=1..19, slot0 = psi0-logit.
__global__ __launch_bounds__(64, 2)
void rnet_kernel(const float* __restrict__ sxy0,
                 const float* __restrict__ sxy,
                 const float* __restrict__ oxy,
                 const float* __restrict__ W_h0, const float* __restrict__ b_h0,
                 const float* __restrict__ W_h1, const float* __restrict__ b_h1,
                 const float* __restrict__ W_ih, const float* __restrict__ b_ih,
                 const float* __restrict__ W_hh, const float* __restrict__ b_hh,
                 const float* __restrict__ W_psi0, const float* __restrict__ b_psi0,
                 const float* __restrict__ W_psi, const float* __restrict__ b_psi,
                 const float* __restrict__ W_p, const float* __restrict__ b_p,
                 float* __restrict__ out)
{
    const int lane = threadIdx.x;       // 0..63 (one wave)
    const int s = lane & 15;            // site within wave / A-row within tile
    const int q = lane >> 4;            // quad
    const int sq = s >> 2, sr = s & 3;
    const int base = blockIdx.x * 16;   // 6250 blocks, exact
    const int site = base + s;

    __shared__ __align__(16) float pL[16 * 20];     // p-logits  [site][k]
    __shared__ __align__(16) float psiL[16 * 20];   // psi-logits; slot0 = psi0
    __shared__ __align__(16) float xs_sh[16 * 19];  // per-site x sequence

    float* __restrict__ out_psi0 = out;                 // [N]
    float* __restrict__ out_psi  = out + NSITES;        // [N,19]
    float* __restrict__ out_p    = out + 20 * NSITES;   // [N,20,2]

    // ==== stage xs (304 floats, coalesced; exact bounds, no clamp) ====
#pragma unroll
    for (int r = 0; r < 5; ++r) {
        int i = r * 64 + lane;
        if (i < 16 * 19) xs_sh[i] = sxy[(size_t)base * 19 + i];
    }
    __syncthreads();   // 1-wave block: cheap fence

    // ==== h0 stage: hs = elu(s0*W_h0+b_h0) in B layout; h0 via permuted W_h1 ====
    f16x8 bf[2];
    {
        const float s0v = sxy0[site];
        f16x8 bf0[2];
#pragma unroll
        for (int kt = 0; kt < 2; ++kt) {
            const float* wp = W_h0 + kt * 32 + q * 8;
            const float* bp = b_h0 + kt * 32 + q * 8;
            float4 w0 = ((const float4*)wp)[0], w1 = ((const float4*)wp)[1];
            float4 c0 = ((const float4*)bp)[0], c1 = ((const float4*)bp)[1];
            float v[8];
            v[0] = eluf_(fmaf(s0v, w0.x, c0.x)); v[1] = eluf_(fmaf(s0v, w0.y, c0.y));
            v[2] = eluf_(fmaf(s0v, w0.z, c0.z)); v[3] = eluf_(fmaf(s0v, w0.w, c0.w));
            v[4] = eluf_(fmaf(s0v, w1.x, c1.x)); v[5] = eluf_(fmaf(s0v, w1.y, c1.y));
            v[6] = eluf_(fmaf(s0v, w1.z, c1.z)); v[7] = eluf_(fmaf(s0v, w1.w, c1.w));
#pragma unroll
            for (int j = 0; j < 8; ++j) bf0[kt][j] = (_Float16)v[j];
        }

        f32x4 acc[4];
#pragma unroll
        for (int mt = 0; mt < 4; ++mt) {
            const int dr = 32 * (mt >> 1) + 8 * q + 4 * (mt & 1);
            float4 b1 = *(const float4*)(b_h1 + dr);
            acc[mt][0] = b1.x; acc[mt][1] = b1.y; acc[mt][2] = b1.z; acc[mt][3] = b1.w;
        }
#pragma unroll
        for (int kt = 0; kt < 2; ++kt)
#pragma unroll
            for (int mt = 0; mt < 4; ++mt) {
                const int ar = 32 * (mt >> 1) + 8 * sq + 4 * (mt & 1) + sr;
                f16x8 a = cvt8h_(W_h1 + ar * HDIM + kt * 32 + q * 8);   // direct global
                acc[mt] = __builtin_amdgcn_mfma_f32_16x16x32_f16(a, bf0[kt], acc[mt], 0, 0, 0);
            }
        FragU f0, f1;
#pragma unroll
        for (int mt = 0; mt < 4; ++mt) {
            hx2 plo; plo[0] = (_Float16)eluf_(acc[mt][0]); plo[1] = (_Float16)eluf_(acc[mt][1]);
            hx2 phi; phi[0] = (_Float16)eluf_(acc[mt][2]); phi[1] = (_Float16)eluf_(acc[mt][3]);
            if (mt < 2) { f0.h2[mt * 2] = plo; f0.h2[mt * 2 + 1] = phi; }
            else        { f1.h2[(mt - 2) * 2] = plo; f1.h2[(mt - 2) * 2 + 1] = phi; }
        }
        bf[0] = f0.v;
        bf[1] = f1.v;
    }

    // ==== persistent loop state: fragments DIRECT from global (L2-hot) ====
    f16x8 a_hh[4][2];
#pragma unroll
    for (int mt = 0; mt < 4; ++mt) {
        const int ar = 32 * (mt >> 1) + 8 * sq + 4 * (mt & 1) + sr;
#pragma unroll
        for (int kt = 0; kt < 2; ++kt)
            a_hh[mt][kt] = cvt8h_(W_hh + ar * HDIM + kt * 32 + q * 8);
    }
    f16x8 a_head[2];
    {
        const float* hrow = (s == 1) ? W_p : ((s == 2) ? W_psi0 : W_psi);
#pragma unroll
        for (int kt = 0; kt < 2; ++kt) a_head[kt] = cvt8h_(hrow + kt * 32 + q * 8);
    }
    f32x4 biasD[4];
    hx2 wih2[4][2];
#pragma unroll
    for (int mt = 0; mt < 4; ++mt) {
        const int dr = 32 * (mt >> 1) + 8 * q + 4 * (mt & 1);
        float4 bi = *(const float4*)(b_ih + dr);
        float4 bh = *(const float4*)(b_hh + dr);
        float4 wi = *(const float4*)(W_ih + dr);
        biasD[mt][0] = bi.x + bh.x; biasD[mt][1] = bi.y + bh.y;
        biasD[mt][2] = bi.z + bh.z; biasD[mt][3] = bi.w + bh.w;
        wih2[mt][0][0] = (_Float16)wi.x; wih2[mt][0][1] = (_Float16)wi.y;
        wih2[mt][1][0] = (_Float16)wi.z; wih2[mt][1][1] = (_Float16)wi.w;
    }
    f32x4 headC;
    headC[0] = (q == 0) ? b_psi[0]  : 0.0f;
    headC[1] = (q == 0) ? b_p[0]    : 0.0f;
    headC[2] = (q == 0) ? b_psi0[0] : 0.0f;
    headC[3] = 0.0f;
    const hx2 z2 = (hx2)(_Float16)0.0f;

    // ==== recurrence: ROLLED, x from LDS pipelined one round ahead ====
    float x = xs_sh[s * 19];           // x for round t=1
#pragma unroll 1
    for (int t = 1; t < NYEARS; ++t) {
        float x_next = (t < NYEARS - 1) ? xs_sh[s * 19 + t] : 0.0f;

        f32x4 acc[4], accH;
#pragma unroll
        for (int mt = 0; mt < 4; ++mt)
            acc[mt] = __builtin_amdgcn_mfma_f32_16x16x32_f16(a_hh[mt][0], bf[0], biasD[mt], 0, 0, 0);
        accH = __builtin_amdgcn_mfma_f32_16x16x32_f16(a_head[0], bf[0], headC, 0, 0, 0);
#pragma unroll
        for (int mt = 0; mt < 4; ++mt)
            acc[mt] = __builtin_amdgcn_mfma_f32_16x16x32_f16(a_hh[mt][1], bf[1], acc[mt], 0, 0, 0);
        accH = __builtin_amdgcn_mfma_f32_16x16x32_f16(a_head[1], bf[1], accH, 0, 0, 0);

        // packed-f16 relu update: hn = max(acc + x*wih, 0); result IS B-frag
        _Float16 xh = (_Float16)x;
        hx2 x2; x2[0] = xh; x2[1] = xh;
        FragU f0, f1;
#pragma unroll
        for (int mt = 0; mt < 4; ++mt) {
            hx2 plo; plo[0] = (_Float16)acc[mt][0]; plo[1] = (_Float16)acc[mt][1];
            hx2 phi; phi[0] = (_Float16)acc[mt][2]; phi[1] = (_Float16)acc[mt][3];
            plo = __builtin_elementwise_max(plo + x2 * wih2[mt][0], z2);
            phi = __builtin_elementwise_max(phi + x2 * wih2[mt][1], z2);
            if (mt < 2) { f0.h2[mt * 2] = plo; f0.h2[mt * 2 + 1] = phi; }
            else        { f1.h2[(mt - 2) * 2] = plo; f1.h2[(mt - 2) * 2 + 1] = phi; }
        }
        bf[0] = f0.v;
        bf[1] = f1.v;

        if (q == 0) {
            // accH is from bf = h_{t-1}: slot (t-1) semantics (R12-validated).
            pL[s * 20 + (t - 1)]   = accH[1];   // p-logit(h_{t-1}), slots 0..18
            psiL[s * 20 + (t - 1)] = accH[0];   // psi-logit(h_{t-1}); slot 0 dead
            if (t == 1) psiL[s * 20] = accH[2]; // overwrite dead slot 0 w/ psi0
        }
        x = x_next;
    }

    // ==== final heads on h_19 ====
    {
        f32x4 accH = __builtin_amdgcn_mfma_f32_16x16x32_f16(a_head[0], bf[0], headC, 0, 0, 0);
        accH = __builtin_amdgcn_mfma_f32_16x16x32_f16(a_head[1], bf[1], accH, 0, 0, 0);
        if (q == 0) {
            pL[s * 20 + 19]   = accH[1];   // p-logit(h_19)
            psiL[s * 20 + 19] = accH[0];   // psi-logit(h_19)
        }
    }

    __syncthreads();   // 1-wave block: LDS fence only

    // ==== epilogue: sigmoid + oxy, 64 threads over 16 sites (exact) ====
    const float wpo = W_p[HDIM];
    if (lane < 16) out_psi0[base + lane] = sigmoidf_(psiL[lane * 20]);
    // psi: 16*19 = 304 floats; flat i = s2*19 + c <- psiL[s2*20 + c+1]
#pragma unroll
    for (int r = 0; r < 5; ++r) {
        int i = r * 64 + lane;
        if (i < 16 * 19) {
            int s2 = i / 19, c = i - s2 * 19;
            out_psi[(size_t)base * 19 + i] = sigmoidf_(psiL[s2 * 20 + c + 1]);
        }
    }
    // p: 16*40 = 640 floats = 160 float4; float4 i4 -> logits pL[i4*2], pL[i4*2+1]
    const float4* oxy_b = (const float4*)(oxy + (size_t)base * 40);
    float4* outp_b = (float4*)(out_p + (size_t)base * 40);
#pragma unroll
    for (int r = 0; r < 3; ++r) {
        int i4 = r * 64 + lane;
        if (i4 < 160) {
            float4 ox = oxy_b[i4];
            float lg0 = pL[i4 * 2];
            float lg1 = pL[i4 * 2 + 1];
            float4 pv;
            pv.x = sigmoidf_(fmaf(wpo, ox.x, lg0));
            pv.y = sigmoidf_(fmaf(wpo, ox.y, lg0));
            pv.z = sigmoidf_(fmaf(wpo, ox.z, lg1));
            pv.w = sigmoidf_(fmaf(wpo, ox.w, lg1));
            outp_b[i4] = pv;
        }
    }
}

extern "C" void kernel_launch(void* const* d_in, const int* in_sizes, int n_in,
                              void* d_out, int out_size, void* d_ws, size_t ws_size,
                              hipStream_t stream) {
    const float* sxy0   = (const float*)d_in[0];
    const float* sxy    = (const float*)d_in[1];
    const float* oxy    = (const float*)d_in[2];
    const float* W_h0   = (const float*)d_in[3];
    const float* b_h0   = (const float*)d_in[4];
    const float* W_h1   = (const float*)d_in[5];
    const float* b_h1   = (const float*)d_in[6];
    const float* W_ih   = (const float*)d_in[7];
    const float* b_ih   = (const float*)d_in[8];
    const float* W_hh   = (const float*)d_in[9];
    const float* b_hh   = (const float*)d_in[10];
    const float* W_psi0 = (const float*)d_in[11];
    const float* b_psi0 = (const float*)d_in[12];
    const float* W_psi  = (const float*)d_in[13];
    const float* b_psi  = (const float*)d_in[14];
    const float* W_p    = (const float*)d_in[15];
    const float* b_p    = (const float*)d_in[16];

    float* out = (float*)d_out;

    dim3 block(64);
    dim3 grid(NSITES / 16);   // 6250 one-wave blocks, 16 sites each (exact)
    rnet_kernel<<<grid, block, 0, stream>>>(
        sxy0, sxy, oxy, W_h0, b_h0, W_h1, b_h1, W_ih, b_ih, W_hh, b_hh,
        W_psi0, b_psi0, W_psi, b_psi, W_p, b_p, out);
}